// Round 4
// baseline (179.179 us; speedup 1.0000x reference)
//
#include <hip/hip_runtime.h>
#include <stdint.h>

#define EPS_F 1e-7f

typedef float f32x4 __attribute__((ext_vector_type(4)));

union A8 { uint2 u2; long l; };

__device__ __forceinline__ unsigned cvt4(float a, float b, float c, float d) {
  int v = __builtin_amdgcn_cvt_pk_fp8_f32(a, b, 0, false);   // bytes 0,1
  return (unsigned)__builtin_amdgcn_cvt_pk_fp8_f32(c, d, v, true);  // bytes 2,3
}

// ---------------------------------------------------------------------------
// prep: prototypes fp32 (2048x512) -> fp8 e4m3 in MFMA B-fragment order for
// 16x16x32 fp8.  16-B chunk (g,kp2), lane l (q=l>>4, cl=l&15) holds
// col n = 16g + cl;  bytes[0:8) = k [64*kp2 + 8q, +8)         (even K32-step)
//                    bytes[8:16) = k [64*kp2 + 32 + 8q, +8)   (odd  K32-step)
// Also y2[c] = ||p_c||^2 (fp32 exact), ry[c] = 1/(1-y2), out = 0, and
// rowmin[] (32768 entries) initialized to +huge (uint bit pattern — float
// compare == uint compare for non-negative floats).
// ---------------------------------------------------------------------------
__global__ __launch_bounds__(256) void prep_kernel(
    const float* __restrict__ protos, uint8_t* __restrict__ wsB,
    float* __restrict__ y2a, float* __restrict__ rya,
    unsigned* __restrict__ rowminU, float* __restrict__ out) {
  const int lane = threadIdx.x & 63;
  const int w    = threadIdx.x >> 6;
  const int kp2  = lane >> 2, q = lane & 3;   // writer coords (lanes 0..31)
  const int sl0  = 8 * kp2 + q;               // source lane of even half
  const int sl1  = sl0 + 4;                   // source lane of odd half
  const int c = blockIdx.x * 4 + w;
  const float4* p = (const float4*)(protos + (size_t)c * 512 + lane * 8);
  float4 f0 = p[0], f1 = p[1];
  float s = f0.x*f0.x + f0.y*f0.y + f0.z*f0.z + f0.w*f0.w
          + f1.x*f1.x + f1.y*f1.y + f1.z*f1.z + f1.w*f1.w;
#pragma unroll
  for (int off = 32; off > 0; off >>= 1) s += __shfl_xor(s, off, 64);
  if (lane == 0) { y2a[c] = s; rya[c] = 1.f / (1.f - s); }
  unsigned ux = cvt4(f0.x, f0.y, f0.z, f0.w);   // this lane's k [8l, 8l+4)
  unsigned uy = cvt4(f1.x, f1.y, f1.z, f1.w);   // k [8l+4, 8l+8)
  uint4 ch;
  ch.x = __shfl((int)ux, sl0, 64);
  ch.y = __shfl((int)uy, sl0, 64);
  ch.z = __shfl((int)ux, sl1, 64);
  ch.w = __shfl((int)uy, sl1, 64);
  if (lane < 32) {
    int g = c >> 4, cl = c & 15;
    ((uint4*)wsB)[((size_t)g * 8 + kp2) * 64 + q * 16 + cl] = ch;
  }
  int tidg = blockIdx.x * 256 + threadIdx.x;   // 131072 threads, 32768 rows
  if (tidg < 32768) rowminU[tidg] = 0x7F7FFFFFu;   // +3.4e38
  if (tidg == 0) out[0] = 0.f;
}

// ---------------------------------------------------------------------------
// gemm_min: 1024 blocks x 256 thr (4 waves), launch_bounds(256,2) -> VGPR
// cap 128 (R0-verified no-spill budget).
// OCCUPANCY MODEL (rounds 0-3): at 128 reported VGPRs the HW fits 3
// waves/SIMD (unified-file quantum + acc regs).  R0's 512-block grid was
// the limiter: exactly 2 blocks/CU.  This version keeps R0's per-wave loop
// BYTE-IDENTICAL (64-row tile, 4 waves, {4 ds_read_b128 + 2 global b128 +
// 16 MFMA} per K=64 iter, 512 MB total B demand) and raises the grid to
// 1024 by splitting the 2048 columns across 2 blocks (col-half h = bid>>9,
// row-tile rt = bid&511 -> pair lands on the same XCD).  3 blocks/CU
// resident = 12 waves/CU = 3 waves/SIMD: +50% latency hiding at R0
// arithmetic intensity.  Cost: z staged twice (128 MB HBM ~ 20 us, hidden
// under 33 us of MFMA) and per-row min combined across col-half blocks via
// uint atomicMin (all values >= 0) into rowminU; acosh/relu/mean moved to a
// tiny finish kernel.
// ---------------------------------------------------------------------------
__global__ __launch_bounds__(256, 2) void gemm_min_kernel(
    const float* __restrict__ z, const uint8_t* __restrict__ wsB,
    const float* __restrict__ y2a, const float* __restrict__ rya,
    float* __restrict__ rxa, unsigned* __restrict__ rowminU) {
  __shared__ uint8_t As[32 * 1024];   // 32 chunks (kp2*4 + rf) x 64 lanes x 16B
  __shared__ float x2s[64];
  __shared__ float minbuf[64][4];

  const int tid  = threadIdx.x;
  const int lane = tid & 63;
  const int w    = tid >> 6;          // wave 0..3
  const int q    = lane >> 4;         // quad 0..3
  const int l15  = lane & 15;
  const int h    = blockIdx.x >> 9;   // column half 0/1
  const int rt   = blockIdx.x & 511;  // row tile
  const size_t rowbase = (size_t)rt * 64;
  const int bb   = h * 512 + w * 128; // this wave's B chunk base

  const uint4* Bg = (const uint4*)wsB;

  // ---- B pipeline warm-up first: overlaps the staging barrier wait ----
  // wave w owns cols [h*1024 + w*256, +256).  iter i = s*8 + kp2 (s=0..7)
  // consumes chunks c0 = bb + s*16 + kp2 and c1 = c0 + 8; slot = i & 3.
  uint4 B0w[4], B1w[4];
#pragma unroll
  for (int i = 0; i < 4; ++i) {
    B0w[i] = Bg[(size_t)(bb + i) * 64 + lane];
    B1w[i] = Bg[(size_t)(bb + 8 + i) * 64 + lane];
  }

  // ---- A staging + fused x2: wave w owns rows w*16 + l15 ----
  // lane (q,l15) covers k slices [64j+8q,+8) and [64j+32+8q,+8) for j=0..7
  {
    const float* rp0 = z + (rowbase + w * 16 + l15) * 512;
    float s = 0.f;
#pragma unroll
    for (int j = 0; j < 8; ++j) {
      const float* rp = rp0 + j * 64 + q * 8;
      float4 a0 = ((const float4*)rp)[0];
      float4 a1 = ((const float4*)rp)[1];
      float4 b0 = ((const float4*)(rp + 32))[0];
      float4 b1 = ((const float4*)(rp + 32))[1];
      s += a0.x*a0.x + a0.y*a0.y + a0.z*a0.z + a0.w*a0.w
         + a1.x*a1.x + a1.y*a1.y + a1.z*a1.z + a1.w*a1.w
         + b0.x*b0.x + b0.y*b0.y + b0.z*b0.z + b0.w*b0.w
         + b1.x*b1.x + b1.y*b1.y + b1.z*b1.z + b1.w*b1.w;
      uint4 ch;
      ch.x = cvt4(a0.x, a0.y, a0.z, a0.w);
      ch.y = cvt4(a1.x, a1.y, a1.z, a1.w);
      ch.z = cvt4(b0.x, b0.y, b0.z, b0.w);
      ch.w = cvt4(b1.x, b1.y, b1.z, b1.w);
      ((uint4*)As)[(j * 4 + w) * 64 + lane] = ch;   // chunk = kp2*4 + rf(=w)
    }
    s += __shfl_xor(s, 16, 64);
    s += __shfl_xor(s, 32, 64);      // sum over the 4 q-lanes of this row
    if (lane < 16) {
      x2s[w * 16 + lane] = s;
      if (h == 0) rxa[rowbase + w * 16 + lane] = 1.f / (1.f - s);
    }
  }
  __syncthreads();  // the ONLY barrier before the final reduction

  // x2 resident per lane: rows rf*16 + q*4 + r
  float x2r[4][4];
#pragma unroll
  for (int rf = 0; rf < 4; ++rf) {
    float4 x4 = *(const float4*)&x2s[rf * 16 + q * 4];
    x2r[rf][0] = x4.x; x2r[rf][1] = x4.y; x2r[rf][2] = x4.z; x2r[rf][3] = x4.w;
  }

  const uint4* Ap = (const uint4*)As;

  float tmin[4][4];
#pragma unroll
  for (int rf = 0; rf < 4; ++rf)
#pragma unroll
    for (int r = 0; r < 4; ++r) tmin[rf][r] = 3.4e38f;

  const float* y2p = y2a + h * 1024 + w * 256 + l15;
  const float* ryp = rya + h * 1024 + w * 256 + l15;

#pragma clang loop unroll(disable)
  for (int s = 0; s < 8; ++s) {
    f32x4 acc[4][2];
#pragma unroll
    for (int rf = 0; rf < 4; ++rf) {
      f32x4 z4 = {0.f, 0.f, 0.f, 0.f};
      acc[rf][0] = z4; acc[rf][1] = z4;
    }
    float y2v0 = y2p[s * 32],      ryv0 = ryp[s * 32];
    float y2v1 = y2p[s * 32 + 16], ryv1 = ryp[s * 32 + 16];

#pragma unroll
    for (int kp2 = 0; kp2 < 8; ++kp2) {
      uint4 bu0 = B0w[kp2 & 3];
      uint4 bu1 = B1w[kp2 & 3];
      {  // prefetch iter i+4 into the just-freed slot (pad absorbs tail)
        int ip = s * 8 + kp2 + 4;
        int sp = ip >> 3, kq = ip & 7;
        size_t c0 = (size_t)(bb + sp * 16 + kq) * 64 + lane;
        B0w[kp2 & 3] = Bg[c0];
        B1w[kp2 & 3] = Bg[c0 + 8 * 64];
      }
      A8 b0lo, b0hi, b1lo, b1hi;
      b0lo.u2 = make_uint2(bu0.x, bu0.y); b0hi.u2 = make_uint2(bu0.z, bu0.w);
      b1lo.u2 = make_uint2(bu1.x, bu1.y); b1hi.u2 = make_uint2(bu1.z, bu1.w);
#pragma unroll
      for (int rf = 0; rf < 4; ++rf) {
        uint4 av = Ap[(kp2 * 4 + rf) * 64 + lane];
        A8 alo, ahi;
        alo.u2 = make_uint2(av.x, av.y);
        ahi.u2 = make_uint2(av.z, av.w);
        acc[rf][0] = __builtin_amdgcn_mfma_f32_16x16x32_fp8_fp8(
            alo.l, b0lo.l, acc[rf][0], 0, 0, 0);
        acc[rf][1] = __builtin_amdgcn_mfma_f32_16x16x32_fp8_fp8(
            alo.l, b1lo.l, acc[rf][1], 0, 0, 0);
        acc[rf][0] = __builtin_amdgcn_mfma_f32_16x16x32_fp8_fp8(
            ahi.l, b0hi.l, acc[rf][0], 0, 0, 0);
        acc[rf][1] = __builtin_amdgcn_mfma_f32_16x16x32_fp8_fp8(
            ahi.l, b1hi.l, acc[rf][1], 0, 0, 0);
      }
    }

    // epilogue: cols c0 = h*1024 + w*256 + s*32 + l15, c1 = c0 + 16
#pragma unroll
    for (int rf = 0; rf < 4; ++rf) {
#pragma unroll
      for (int r = 0; r < 4; ++r) {
        float xv = x2r[rf][r];
        float u0 = fmaxf(fmaf(-2.f, acc[rf][0][r], xv + y2v0), 0.f) * ryv0;
        float u1 = fmaxf(fmaf(-2.f, acc[rf][1][r], xv + y2v1), 0.f) * ryv1;
        tmin[rf][r] = fminf(tmin[rf][r], fminf(u0, u1));
      }
    }
  }

  // ---- min across the 16 lanes (l15) sharing each row ----
#pragma unroll
  for (int rf = 0; rf < 4; ++rf) {
#pragma unroll
    for (int r = 0; r < 4; ++r) {
      float v = tmin[rf][r];
      v = fminf(v, __shfl_xor(v, 1, 64));
      v = fminf(v, __shfl_xor(v, 2, 64));
      v = fminf(v, __shfl_xor(v, 4, 64));
      v = fminf(v, __shfl_xor(v, 8, 64));
      if (l15 == 0) minbuf[rf * 16 + q * 4 + r][w] = v;
    }
  }
  __syncthreads();

  if (w == 0) {  // lane = row 0..63; combine col-halves via uint atomicMin
    float m = fminf(fminf(minbuf[lane][0], minbuf[lane][1]),
                    fminf(minbuf[lane][2], minbuf[lane][3]));
    atomicMin(&rowminU[rowbase + lane], __float_as_uint(m));
  }
}

// ---------------------------------------------------------------------------
// finish: per row, fold 1/(1-x2), arccosh, relu(margin - d), mean.
// 32768 rows, one thread each: 256 KB of reads + 512 atomicAdds, ~5 us.
// ---------------------------------------------------------------------------
__global__ __launch_bounds__(256) void finish_kernel(
    const unsigned* __restrict__ rowminU, const float* __restrict__ rxa,
    const float* __restrict__ marg, float* __restrict__ out) {
  const int row  = blockIdx.x * 256 + threadIdx.x;
  const int lane = threadIdx.x & 63;
  float m = __uint_as_float(rowminU[row]);
  float t = m * rxa[row];                  // monotone: rx > 0
  float arg = fmaxf(fmaf(2.f, t, 1.f), 1.f + EPS_F);
  float contrib = fmaxf(marg[0] - acoshf(arg), 0.f);
#pragma unroll
  for (int off = 32; off > 0; off >>= 1) contrib += __shfl_xor(contrib, off, 64);
  if (lane == 0) atomicAdd(out, contrib * (1.0f / 32768.f));
}

// ---------------------------------------------------------------------------
extern "C" void kernel_launch(void* const* d_in, const int* in_sizes, int n_in,
                              void* d_out, int out_size, void* d_ws, size_t ws_size,
                              hipStream_t stream) {
  const float* z      = (const float*)d_in[0];  // 32768 x 512 fp32
  const float* protos = (const float*)d_in[1];  // 2048 x 512 fp32
  const float* marg   = (const float*)d_in[2];  // scalar
  float* out = (float*)d_out;
  uint8_t* wsB = (uint8_t*)d_ws;                                 // 1 MB image
  // 192 KB pad absorbs the harmless B-pipeline tail over-reads (<= 64 KB).
  char* base = (char*)d_ws + (1 << 20) + 192 * 1024;
  float*    y2a     = (float*)base;                // 8 KB
  float*    rya     = y2a + 2048;                  // 8 KB
  float*    rxa     = rya + 2048;                  // 128 KB (per-row 1/(1-x2))
  unsigned* rowminU = (unsigned*)(rxa + 32768);    // 128 KB (per-row min)

  prep_kernel<<<512, 256, 0, stream>>>(protos, wsB, y2a, rya, rowminU, out);
  gemm_min_kernel<<<1024, 256, 0, stream>>>(z, wsB, y2a, rya, rxa, rowminU);
  finish_kernel<<<128, 256, 0, stream>>>(rowminU, rxa, marg, out);
}

// Round 5
// 147.080 us; speedup vs baseline: 1.2182x; 1.2182x over previous
//
#include <hip/hip_runtime.h>
#include <stdint.h>

#define EPS_F 1e-7f

typedef float f32x4 __attribute__((ext_vector_type(4)));
typedef int   v8i   __attribute__((ext_vector_type(8)));

// 8 consecutive VGPRs: two b128 loads land directly in the MFMA operand tuple.
union A32 { uint4 u4[2]; v8i v; };

__device__ __forceinline__ unsigned cvt4(float a, float b, float c, float d) {
  int v = __builtin_amdgcn_cvt_pk_fp8_f32(a, b, 0, false);   // bytes 0,1
  return (unsigned)__builtin_amdgcn_cvt_pk_fp8_f32(c, d, v, true);  // bytes 2,3
}

// MX-scaled fp8 MFMA, K=128, scales = 1.0 (e8m0 127 in every byte -> opsel-proof).
// cbsz=0 (A fmt fp8 e4m3), blgp=0 (B fmt fp8 e4m3).
#define MFMA128(A, B, C) __builtin_amdgcn_mfma_scale_f32_16x16x128_f8f6f4( \
    (A), (B), (C), 0, 0, 0, 0x7F7F7F7F, 0, 0x7F7F7F7F)

// ---------------------------------------------------------------------------
// Shared software k-order for BOTH operand images (permutation-invariance over
// K + symmetric A/B fragment layouts make any HW intra-instruction k-mapping
// cancel, as long as A and B use the same (lane,byte)->k function):
//   fragment lane = kg*16 + (row|col)&15,  kg = lane>>4
//   nominal k  = kb*128 + kg*32 + j,  j in [0,32)
//   j in [0,16)  -> LO plane (one b128),  j in [16,32) -> HI plane (one b128)
// B image: run index ri = (g*4 + kb)*64 + lane, planes of 512 KB each.
// ---------------------------------------------------------------------------

// ---------------------------------------------------------------------------
// prep: protos fp32 (2048x512) -> fp8 e4m3 B image in the layout above.
// Lane l of proto c holds k [8l, 8l+8): kb = l>>4, kg = (l>>2)&3, j = 8*(l&3)
// -> each lane stores ONE aligned uint2, no cross-lane shuffles needed.
// Also y2[c] = ||p_c||^2 (fp32 exact), ry[c] = 1/(1-y2), out = 0.
// ---------------------------------------------------------------------------
__global__ __launch_bounds__(256) void prep_kernel(
    const float* __restrict__ protos, uint8_t* __restrict__ wsB,
    float* __restrict__ y2a, float* __restrict__ rya,
    float* __restrict__ out) {
  const int lane = threadIdx.x & 63;
  const int w    = threadIdx.x >> 6;
  const int c    = blockIdx.x * 4 + w;
  const int g    = c >> 4, cl = c & 15;
  const float4* p = (const float4*)(protos + (size_t)c * 512 + lane * 8);
  float4 f0 = p[0], f1 = p[1];
  float s = f0.x*f0.x + f0.y*f0.y + f0.z*f0.z + f0.w*f0.w
          + f1.x*f1.x + f1.y*f1.y + f1.z*f1.z + f1.w*f1.w;
#pragma unroll
  for (int off = 32; off > 0; off >>= 1) s += __shfl_xor(s, off, 64);
  if (lane == 0) { y2a[c] = s; rya[c] = 1.f / (1.f - s); }
  unsigned ux = cvt4(f0.x, f0.y, f0.z, f0.w);   // k [8l, 8l+4)
  unsigned uy = cvt4(f1.x, f1.y, f1.z, f1.w);   // k [8l+4, 8l+8)
  const int kb = lane >> 4, kg = (lane >> 2) & 3, bo = lane & 3;
  size_t ri  = (size_t)(g * 4 + kb) * 64 + kg * 16 + cl;
  size_t off = ri * 16 + (size_t)(bo & 1) * 8 + (size_t)(bo >> 1) * (512u * 1024u);
  *(uint2*)(wsB + off) = make_uint2(ux, uy);
  if (blockIdx.x == 0 && threadIdx.x == 0) out[0] = 0.f;
}

// ---------------------------------------------------------------------------
// gemm_min: 512 blocks x 256 thr (4 waves), launch_bounds(256,1) -> VGPR cap
// 256 (no spill; R2/R3 proved the (.,2+) caps spill this loop).
// OCCUPANCY MODEL (rounds 0-4, final): residency is pinned at 2 waves/SIMD
// for ANY config of this loop (128 arch + 32 acc VGPRs -> 192-granule ->
// 512/192 = 2); grid/block reshaping never moved it (R0 18.9%, R3 20.4%,
// R4 20.2%).  So this round buys PER-INSTRUCTION work instead: MX-scaled
// mfma_scale_f32_16x16x128_f8f6f4 (scale=1.0, same e4m3 bytes -> identical
// quantization), 2x rate + 4x fewer instructions than 16x16x32.
//   - geometry: R0-proven 64 rows x 2048 cols, 4 waves x 512-col strips,
//     fold-finish in-kernel (FETCH back to one z pass, B demand 512 MB
//     L2-resident).
//   - A: 64x512 fp8 staged ONCE into 2x16 KB LDS planes (lo/hi 16-B halves
//     of each 32-B k-run; all LDS ops the proven stride-16 b128 pattern);
//     x2 fused fp32-exact.  ONE barrier before the main loop.
//   - B: register pipeline in A32 unions (loads land in the MFMA operand
//     tuples, no repack movs), 4 kb-slots = one full s-strip lookahead
//     (~275 cyc of MFMA cover at the MX rate).
//   - per step (kb): 8 ds_read_b128 (A) + 4 global b128 (B prefetch) +
//     8 MFMA(K=128).  MFMA floor 14.7 us, LDS floor ~13.7 us.
//   - epilogue per 32-col strip unchanged: tmin = min(tmin,
//     max(x2+y2-2dot,0)*ry); 1/(1-x2) folded once per row (monotone).
// ---------------------------------------------------------------------------
__global__ __launch_bounds__(256, 1) void gemm_min_kernel(
    const float* __restrict__ z, const uint8_t* __restrict__ wsB,
    const float* __restrict__ y2a, const float* __restrict__ rya,
    const float* __restrict__ marg, float* __restrict__ out) {
  __shared__ uint4 AsLo[1024];   // (kb*4 + rf)*64 + lane   (16 KB)
  __shared__ uint4 AsHi[1024];   // same index, k-bytes 16..31 (16 KB)
  __shared__ float x2s[64];
  __shared__ float rxs[64];
  __shared__ float minbuf[64][4];

  const int tid  = threadIdx.x;
  const int lane = tid & 63;
  const int w    = tid >> 6;          // wave 0..3
  const int q    = lane >> 4;         // kg / acc row-group
  const int l15  = lane & 15;
  const size_t rowbase = (size_t)blockIdx.x * 64;

  const uint4* BLo = (const uint4*)wsB;
  const uint4* BHi = BLo + 32768;     // +512 KB

  // ---- B warm-up (s=0, kb=0..3) first: overlaps the staging barrier ----
  // wave w owns frags g in [w*32, +32); step (s,kb): g0 = w*32 + 2s, g1 = g0+1
  // run index ri = (g*4 + kb)*64 + lane; slot = kb.
  A32 Bp0[4], Bp1[4];
#pragma unroll
  for (int i = 0; i < 4; ++i) {
    size_t r0 = (size_t)(w * 128 + i) * 64 + lane;   // (w*32*4 + i)*64
    Bp0[i].u4[0] = BLo[r0];       Bp0[i].u4[1] = BHi[r0];
    Bp1[i].u4[0] = BLo[r0 + 256]; Bp1[i].u4[1] = BHi[r0 + 256];  // g1 -> +4*64
  }

  // ---- A staging + fused x2: wave w(=rf) owns rows w*16 + l15 ----
  // lane (q,l15): k quarter [q*128, +128) of its row, 4 sub-runs of 32.
  {
    const float* rp0 = z + (rowbase + w * 16 + l15) * 512 + q * 128;
    float s = 0.f;
#pragma unroll
    for (int t = 0; t < 4; ++t) {
      const float4* rp = (const float4*)(rp0 + t * 32);
      float4 v0 = rp[0], v1 = rp[1], v2 = rp[2], v3 = rp[3];
      float4 v4 = rp[4], v5 = rp[5], v6 = rp[6], v7 = rp[7];
      s += v0.x*v0.x + v0.y*v0.y + v0.z*v0.z + v0.w*v0.w
         + v1.x*v1.x + v1.y*v1.y + v1.z*v1.z + v1.w*v1.w
         + v2.x*v2.x + v2.y*v2.y + v2.z*v2.z + v2.w*v2.w
         + v3.x*v3.x + v3.y*v3.y + v3.z*v3.z + v3.w*v3.w
         + v4.x*v4.x + v4.y*v4.y + v4.z*v4.z + v4.w*v4.w
         + v5.x*v5.x + v5.y*v5.y + v5.z*v5.z + v5.w*v5.w
         + v6.x*v6.x + v6.y*v6.y + v6.z*v6.z + v6.w*v6.w
         + v7.x*v7.x + v7.y*v7.y + v7.z*v7.z + v7.w*v7.w;
      uint4 lo, hi;
      lo.x = cvt4(v0.x, v0.y, v0.z, v0.w);
      lo.y = cvt4(v1.x, v1.y, v1.z, v1.w);
      lo.z = cvt4(v2.x, v2.y, v2.z, v2.w);
      lo.w = cvt4(v3.x, v3.y, v3.z, v3.w);
      hi.x = cvt4(v4.x, v4.y, v4.z, v4.w);
      hi.y = cvt4(v5.x, v5.y, v5.z, v5.w);
      hi.z = cvt4(v6.x, v6.y, v6.z, v6.w);
      hi.w = cvt4(v7.x, v7.y, v7.z, v7.w);
      int ri = (q * 4 + w) * 64 + t * 16 + l15;   // chunk (kb=q, rf=w), kg=t
      AsLo[ri] = lo; AsHi[ri] = hi;
    }
    s += __shfl_xor(s, 16, 64);
    s += __shfl_xor(s, 32, 64);      // sum over the 4 q-lanes of this row
    if (lane < 16) { x2s[w * 16 + lane] = s; rxs[w * 16 + lane] = 1.f / (1.f - s); }
  }
  __syncthreads();  // the ONLY barrier before the final reduction

  // x2 resident per lane: rows rf*16 + q*4 + r
  float x2r[4][4];
#pragma unroll
  for (int rf = 0; rf < 4; ++rf) {
    float4 x4 = *(const float4*)&x2s[rf * 16 + q * 4];
    x2r[rf][0] = x4.x; x2r[rf][1] = x4.y; x2r[rf][2] = x4.z; x2r[rf][3] = x4.w;
  }

  float tmin[4][4];
#pragma unroll
  for (int rf = 0; rf < 4; ++rf)
#pragma unroll
    for (int r = 0; r < 4; ++r) tmin[rf][r] = 3.4e38f;

  const float* y2p = y2a + w * 512 + l15;
  const float* ryp = rya + w * 512 + l15;

#pragma clang loop unroll(disable)
  for (int s = 0; s < 16; ++s) {
    f32x4 acc[4][2];
#pragma unroll
    for (int rf = 0; rf < 4; ++rf) {
      f32x4 z4 = {0.f, 0.f, 0.f, 0.f};
      acc[rf][0] = z4; acc[rf][1] = z4;
    }
    float y2v0 = y2p[s * 32],      ryv0 = ryp[s * 32];
    float y2v1 = y2p[s * 32 + 16], ryv1 = ryp[s * 32 + 16];

#pragma unroll
    for (int kb = 0; kb < 4; ++kb) {
      v8i bv0 = Bp0[kb].v;
      v8i bv1 = Bp1[kb].v;
      {  // prefetch step (s+1, kb) into the just-freed slot (pad absorbs tail)
        size_t r0 = ((size_t)(w * 32 + 2 * (s + 1)) * 4 + kb) * 64 + lane;
        Bp0[kb].u4[0] = BLo[r0];       Bp0[kb].u4[1] = BHi[r0];
        Bp1[kb].u4[0] = BLo[r0 + 256]; Bp1[kb].u4[1] = BHi[r0 + 256];
      }
#pragma unroll
      for (int rf = 0; rf < 4; ++rf) {
        A32 a;
        int ri = (kb * 4 + rf) * 64 + lane;
        a.u4[0] = AsLo[ri];
        a.u4[1] = AsHi[ri];
        acc[rf][0] = MFMA128(a.v, bv0, acc[rf][0]);
        acc[rf][1] = MFMA128(a.v, bv1, acc[rf][1]);
      }
    }

    // epilogue: cols c0 = w*512 + s*32 + l15, c1 = c0 + 16
#pragma unroll
    for (int rf = 0; rf < 4; ++rf) {
#pragma unroll
      for (int r = 0; r < 4; ++r) {
        float xv = x2r[rf][r];
        float u0 = fmaxf(fmaf(-2.f, acc[rf][0][r], xv + y2v0), 0.f) * ryv0;
        float u1 = fmaxf(fmaf(-2.f, acc[rf][1][r], xv + y2v1), 0.f) * ryv1;
        tmin[rf][r] = fminf(tmin[rf][r], fminf(u0, u1));
      }
    }
  }

  // ---- min across the 16 lanes (l15) sharing each row ----
#pragma unroll
  for (int rf = 0; rf < 4; ++rf) {
#pragma unroll
    for (int r = 0; r < 4; ++r) {
      float v = tmin[rf][r];
      v = fminf(v, __shfl_xor(v, 1, 64));
      v = fminf(v, __shfl_xor(v, 2, 64));
      v = fminf(v, __shfl_xor(v, 4, 64));
      v = fminf(v, __shfl_xor(v, 8, 64));
      if (l15 == 0) minbuf[rf * 16 + q * 4 + r][w] = v;
    }
  }
  __syncthreads();

  if (w == 0) {  // lane = row 0..63
    float m = fminf(fminf(minbuf[lane][0], minbuf[lane][1]),
                    fminf(minbuf[lane][2], minbuf[lane][3]));
    float t = m * rxs[lane];                 // fold 1/(1-x2) once per row
    float arg = fmaxf(fmaf(2.f, t, 1.f), 1.f + EPS_F);
    float contrib = fmaxf(marg[0] - acoshf(arg), 0.f);
#pragma unroll
    for (int off = 32; off > 0; off >>= 1) contrib += __shfl_xor(contrib, off, 64);
    if (lane == 0) atomicAdd(out, contrib * (1.0f / 32768.f));
  }
}

// ---------------------------------------------------------------------------
extern "C" void kernel_launch(void* const* d_in, const int* in_sizes, int n_in,
                              void* d_out, int out_size, void* d_ws, size_t ws_size,
                              hipStream_t stream) {
  const float* z      = (const float*)d_in[0];  // 32768 x 512 fp32
  const float* protos = (const float*)d_in[1];  // 2048 x 512 fp32
  const float* marg   = (const float*)d_in[2];  // scalar
  float* out = (float*)d_out;
  uint8_t* wsB = (uint8_t*)d_ws;                // 1 MB image (lo/hi 512 KB planes)
  // 192 KB pad absorbs the harmless B-pipeline tail over-reads (<= 32 KB).
  float* y2a = (float*)((char*)d_ws + (1 << 20) + 192 * 1024);   // 8 KB
  float* rya = y2a + 2048;                                       // 8 KB

  prep_kernel<<<512, 256, 0, stream>>>(protos, wsB, y2a, rya, out);
  gemm_min_kernel<<<512, 256, 0, stream>>>(z, wsB, y2a, rya, marg, out);
}

// Round 6
// 135.517 us; speedup vs baseline: 1.3222x; 1.0853x over previous
//
#include <hip/hip_runtime.h>
#include <stdint.h>

#define EPS_F 1e-7f

typedef float f32x4 __attribute__((ext_vector_type(4)));
typedef int   v8i   __attribute__((ext_vector_type(8)));

// 8 consecutive VGPRs: two b128 loads land directly in the MFMA operand tuple.
union A32 { uint4 u4[2]; v8i v; };

__device__ __forceinline__ unsigned cvt4(float a, float b, float c, float d) {
  int v = __builtin_amdgcn_cvt_pk_fp8_f32(a, b, 0, false);   // bytes 0,1
  return (unsigned)__builtin_amdgcn_cvt_pk_fp8_f32(c, d, v, true);  // bytes 2,3
}

// MX-scaled fp8 MFMA, K=128, scales = 1.0 (e8m0 127 in every byte -> opsel-proof).
// cbsz=0 (A fmt fp8 e4m3), blgp=0 (B fmt fp8 e4m3).
#define MFMA128(A, B, C) __builtin_amdgcn_mfma_scale_f32_16x16x128_f8f6f4( \
    (A), (B), (C), 0, 0, 0, 0x7F7F7F7F, 0, 0x7F7F7F7F)

// ---------------------------------------------------------------------------
// Shared software k-order for BOTH operand images (permutation-invariance over
// K + symmetric A/B fragment layouts make any HW intra-instruction k-mapping
// cancel, as long as A and B use the same (lane,byte)->k function):
//   fragment lane = kg*16 + (row|col)&15,  kg = lane>>4
//   nominal k  = kb*128 + kg*32 + j,  j in [0,32)
//   j in [0,16)  -> LO plane (one b128),  j in [16,32) -> HI plane (one b128)
// B image: run index ri = (g*4 + kb)*64 + lane, planes of 512 KB each.
// R5 verified this end-to-end (absmax 0).
// ---------------------------------------------------------------------------

// ---------------------------------------------------------------------------
// prep: protos fp32 (2048x512) -> fp8 e4m3 B image in the layout above.
// Lane l of proto c holds k [8l, 8l+8): kb = l>>4, kg = (l>>2)&3, j = 8*(l&3)
// -> each lane stores ONE aligned uint2, no cross-lane shuffles needed.
// Also y2[c] = ||p_c||^2 (fp32 exact), ry[c] = 1/(1-y2), out = 0.
// (unchanged from R5 — verified)
// ---------------------------------------------------------------------------
__global__ __launch_bounds__(256) void prep_kernel(
    const float* __restrict__ protos, uint8_t* __restrict__ wsB,
    float* __restrict__ y2a, float* __restrict__ rya,
    float* __restrict__ out) {
  const int lane = threadIdx.x & 63;
  const int w    = threadIdx.x >> 6;
  const int c    = blockIdx.x * 4 + w;
  const int g    = c >> 4, cl = c & 15;
  const float4* p = (const float4*)(protos + (size_t)c * 512 + lane * 8);
  float4 f0 = p[0], f1 = p[1];
  float s = f0.x*f0.x + f0.y*f0.y + f0.z*f0.z + f0.w*f0.w
          + f1.x*f1.x + f1.y*f1.y + f1.z*f1.z + f1.w*f1.w;
#pragma unroll
  for (int off = 32; off > 0; off >>= 1) s += __shfl_xor(s, off, 64);
  if (lane == 0) { y2a[c] = s; rya[c] = 1.f / (1.f - s); }
  unsigned ux = cvt4(f0.x, f0.y, f0.z, f0.w);   // k [8l, 8l+4)
  unsigned uy = cvt4(f1.x, f1.y, f1.z, f1.w);   // k [8l+4, 8l+8)
  const int kb = lane >> 4, kg = (lane >> 2) & 3, bo = lane & 3;
  size_t ri  = (size_t)(g * 4 + kb) * 64 + kg * 16 + cl;
  size_t off = ri * 16 + (size_t)(bo & 1) * 8 + (size_t)(bo >> 1) * (512u * 1024u);
  *(uint2*)(wsB + off) = make_uint2(ux, uy);
  if (blockIdx.x == 0 && threadIdx.x == 0) out[0] = 0.f;
}

// ---------------------------------------------------------------------------
// gemm_min v6: 512 blocks x 512 thr (8 waves), launch_bounds(512,1) -> VGPR
// cap 128 (R3-measured).
// ROUND-5 DIAGNOSIS: MFMA busy time (0.18 x 70us = 12.6us) already equals
// the 14.7us MX floor — the pipe runs at full rate when fed; duration is
// stall time at 2 waves/SIMD (VGPR 168 -> occupancy halved to 10%).  Fix =
// shrink the steady-state register set and double TLP:
//   - 16-col s-strips: ONE B frag per s-iter -> Bp pipeline 4 slots x 8
//     = 32 VGPRs (was 64), acc 16 (was 32).  Live set ~108 < 128 cap.
//   - 8-wave blocks, grid 512 -> 2 blocks/CU x 8 waves = 4 waves/SIMD
//     (2x R5), LDS 2 x 34.5KB = 69KB, VGPR 4 x 128 = 512 exactly.
//   - per kb-step: 8 ds_read_b128 (A, 4 rf frags) + 2 global b128 (B
//     prefetch, 4-kb-step = ~550cyc lookahead) + 4 MFMA(K=128).
//   - A staging: byte-identical R5 code on waves 0..3 (16 rows each);
//     waves 4..7 issue B warm-up then wait at the single barrier.
//   - epilogue per 16-col strip: tmin = min(tmin, max(x2+y2-2dot,0)*ry);
//     1/(1-x2) folded once per row at the end (monotone, rx>0).
// ---------------------------------------------------------------------------
__global__ __launch_bounds__(512, 1) void gemm_min_kernel(
    const float* __restrict__ z, const uint8_t* __restrict__ wsB,
    const float* __restrict__ y2a, const float* __restrict__ rya,
    const float* __restrict__ marg, float* __restrict__ out) {
  __shared__ uint4 AsLo[1024];   // (kb*4 + rf)*64 + lane   (16 KB)
  __shared__ uint4 AsHi[1024];   // same index, k-bytes 16..31 (16 KB)
  __shared__ float x2s[64];
  __shared__ float rxs[64];
  __shared__ float minbuf[64][8];

  const int tid  = threadIdx.x;
  const int lane = tid & 63;
  const int w    = tid >> 6;          // wave 0..7
  const int q    = lane >> 4;         // kg / acc row-group
  const int l15  = lane & 15;
  const size_t rowbase = (size_t)blockIdx.x * 64;

  const uint4* BLo = (const uint4*)wsB;
  const uint4* BHi = BLo + 32768;     // +512 KB

  // ---- B warm-up (s=0, kb=0..3) first: overlaps the staging barrier ----
  // wave w owns cols [w*256, +256): frag g = w*16 + s, s in [0,16).
  // chunk ri = (g*4 + kb)*64 + lane; slot = kb.
  A32 Bp[4];
#pragma unroll
  for (int i = 0; i < 4; ++i) {
    size_t r0 = (size_t)(w * 64 + i) * 64 + lane;   // ((w*16+0)*4 + i)*64
    Bp[i].u4[0] = BLo[r0];
    Bp[i].u4[1] = BHi[r0];
  }

  // ---- A staging + fused x2: waves 0..3 own rows w*16 + l15 (R5 code) ----
  // lane (q,l15): k quarter [q*128, +128) of its row, 4 sub-runs of 32.
  if (w < 4) {
    const float* rp0 = z + (rowbase + w * 16 + l15) * 512 + q * 128;
    float s = 0.f;
#pragma unroll
    for (int t = 0; t < 4; ++t) {
      const float4* rp = (const float4*)(rp0 + t * 32);
      float4 v0 = rp[0], v1 = rp[1], v2 = rp[2], v3 = rp[3];
      float4 v4 = rp[4], v5 = rp[5], v6 = rp[6], v7 = rp[7];
      s += v0.x*v0.x + v0.y*v0.y + v0.z*v0.z + v0.w*v0.w
         + v1.x*v1.x + v1.y*v1.y + v1.z*v1.z + v1.w*v1.w
         + v2.x*v2.x + v2.y*v2.y + v2.z*v2.z + v2.w*v2.w
         + v3.x*v3.x + v3.y*v3.y + v3.z*v3.z + v3.w*v3.w
         + v4.x*v4.x + v4.y*v4.y + v4.z*v4.z + v4.w*v4.w
         + v5.x*v5.x + v5.y*v5.y + v5.z*v5.z + v5.w*v5.w
         + v6.x*v6.x + v6.y*v6.y + v6.z*v6.z + v6.w*v6.w
         + v7.x*v7.x + v7.y*v7.y + v7.z*v7.z + v7.w*v7.w;
      uint4 lo, hi;
      lo.x = cvt4(v0.x, v0.y, v0.z, v0.w);
      lo.y = cvt4(v1.x, v1.y, v1.z, v1.w);
      lo.z = cvt4(v2.x, v2.y, v2.z, v2.w);
      lo.w = cvt4(v3.x, v3.y, v3.z, v3.w);
      hi.x = cvt4(v4.x, v4.y, v4.z, v4.w);
      hi.y = cvt4(v5.x, v5.y, v5.z, v5.w);
      hi.z = cvt4(v6.x, v6.y, v6.z, v6.w);
      hi.w = cvt4(v7.x, v7.y, v7.z, v7.w);
      int ri = (q * 4 + w) * 64 + t * 16 + l15;   // chunk (kb=q, rf=w), kg=t
      AsLo[ri] = lo; AsHi[ri] = hi;
    }
    s += __shfl_xor(s, 16, 64);
    s += __shfl_xor(s, 32, 64);      // sum over the 4 q-lanes of this row
    if (lane < 16) { x2s[w * 16 + lane] = s; rxs[w * 16 + lane] = 1.f / (1.f - s); }
  }
  __syncthreads();  // the ONLY barrier before the final reduction

  // x2 resident per lane: rows rf*16 + q*4 + r
  float x2r[4][4];
#pragma unroll
  for (int rf = 0; rf < 4; ++rf) {
    float4 x4 = *(const float4*)&x2s[rf * 16 + q * 4];
    x2r[rf][0] = x4.x; x2r[rf][1] = x4.y; x2r[rf][2] = x4.z; x2r[rf][3] = x4.w;
  }

  float tmin[4][4];
#pragma unroll
  for (int rf = 0; rf < 4; ++rf)
#pragma unroll
    for (int r = 0; r < 4; ++r) tmin[rf][r] = 3.4e38f;

  const float* y2p = y2a + w * 256 + l15;
  const float* ryp = rya + w * 256 + l15;

#pragma clang loop unroll(disable)
  for (int s = 0; s < 16; ++s) {
    f32x4 acc[4];
#pragma unroll
    for (int rf = 0; rf < 4; ++rf) {
      f32x4 z4 = {0.f, 0.f, 0.f, 0.f};
      acc[rf] = z4;
    }
    float y2v = y2p[s * 16], ryv = ryp[s * 16];

#pragma unroll
    for (int kb = 0; kb < 4; ++kb) {
      v8i bv = Bp[kb].v;
      {  // prefetch (s+1, kb) into the just-freed slot (pad absorbs tail)
        size_t r0 = ((size_t)(w * 16 + s + 1) * 4 + kb) * 64 + lane;
        Bp[kb].u4[0] = BLo[r0];
        Bp[kb].u4[1] = BHi[r0];
      }
#pragma unroll
      for (int rf = 0; rf < 4; ++rf) {
        A32 a;
        int ri = (kb * 4 + rf) * 64 + lane;
        a.u4[0] = AsLo[ri];
        a.u4[1] = AsHi[ri];
        acc[rf] = MFMA128(a.v, bv, acc[rf]);
      }
    }

    // epilogue: cols c = w*256 + s*16 + l15
#pragma unroll
    for (int rf = 0; rf < 4; ++rf) {
#pragma unroll
      for (int r = 0; r < 4; ++r) {
        float u = fmaxf(fmaf(-2.f, acc[rf][r], x2r[rf][r] + y2v), 0.f) * ryv;
        tmin[rf][r] = fminf(tmin[rf][r], u);
      }
    }
  }

  // ---- min across the 16 lanes (l15) sharing each row ----
#pragma unroll
  for (int rf = 0; rf < 4; ++rf) {
#pragma unroll
    for (int r = 0; r < 4; ++r) {
      float v = tmin[rf][r];
      v = fminf(v, __shfl_xor(v, 1, 64));
      v = fminf(v, __shfl_xor(v, 2, 64));
      v = fminf(v, __shfl_xor(v, 4, 64));
      v = fminf(v, __shfl_xor(v, 8, 64));
      if (l15 == 0) minbuf[rf * 16 + q * 4 + r][w] = v;
    }
  }
  __syncthreads();

  if (w == 0) {  // lane = row 0..63
    float m = minbuf[lane][0];
#pragma unroll
    for (int i = 1; i < 8; ++i) m = fminf(m, minbuf[lane][i]);
    float t = m * rxs[lane];                 // fold 1/(1-x2) once per row
    float arg = fmaxf(fmaf(2.f, t, 1.f), 1.f + EPS_F);
    float contrib = fmaxf(marg[0] - acoshf(arg), 0.f);
#pragma unroll
    for (int off = 32; off > 0; off >>= 1) contrib += __shfl_xor(contrib, off, 64);
    if (lane == 0) atomicAdd(out, contrib * (1.0f / 32768.f));
  }
}

// ---------------------------------------------------------------------------
extern "C" void kernel_launch(void* const* d_in, const int* in_sizes, int n_in,
                              void* d_out, int out_size, void* d_ws, size_t ws_size,
                              hipStream_t stream) {
  const float* z      = (const float*)d_in[0];  // 32768 x 512 fp32
  const float* protos = (const float*)d_in[1];  // 2048 x 512 fp32
  const float* marg   = (const float*)d_in[2];  // scalar
  float* out = (float*)d_out;
  uint8_t* wsB = (uint8_t*)d_ws;                // 1 MB image (lo/hi 512 KB planes)
  // 192 KB pad absorbs the harmless B-pipeline tail over-reads (<= 32 KB).
  float* y2a = (float*)((char*)d_ws + (1 << 20) + 192 * 1024);   // 8 KB
  float* rya = y2a + 2048;                                       // 8 KB

  prep_kernel<<<512, 256, 0, stream>>>(protos, wsB, y2a, rya, out);
  gemm_min_kernel<<<512, 512, 0, stream>>>(z, wsB, y2a, rya, marg, out);
}

// Round 7
// 134.849 us; speedup vs baseline: 1.3287x; 1.0049x over previous
//
#include <hip/hip_runtime.h>
#include <stdint.h>

#define EPS_F 1e-7f

typedef float f32x4 __attribute__((ext_vector_type(4)));
typedef int   v8i   __attribute__((ext_vector_type(8)));

// 8 consecutive VGPRs: two b128 loads land directly in the MFMA operand tuple.
union A32 { uint4 u4[2]; v8i v; };

__device__ __forceinline__ unsigned cvt4(float a, float b, float c, float d) {
  int v = __builtin_amdgcn_cvt_pk_fp8_f32(a, b, 0, false);   // bytes 0,1
  return (unsigned)__builtin_amdgcn_cvt_pk_fp8_f32(c, d, v, true);  // bytes 2,3
}

// MX-scaled fp8 MFMA, K=128, scales = 1.0 (e8m0 127 in every byte -> opsel-proof).
// cbsz=0 (A fmt fp8 e4m3), blgp=0 (B fmt fp8 e4m3).
#define MFMA128(A, B, C) __builtin_amdgcn_mfma_scale_f32_16x16x128_f8f6f4( \
    (A), (B), (C), 0, 0, 0, 0x7F7F7F7F, 0, 0x7F7F7F7F)

// ---------------------------------------------------------------------------
// Shared software k-order for BOTH operand images (permutation-invariance over
// K + symmetric A/B fragment layouts make any HW intra-instruction k-mapping
// cancel, as long as A and B use the same (lane,byte)->k function):
//   fragment lane = kg*16 + (row|col)&15,  kg = lane>>4
//   nominal k  = kb*128 + kg*32 + j,  j in [0,32)
//   j in [0,16)  -> LO plane (one b128),  j in [16,32) -> HI plane (one b128)
// B image: run index ri = (g*4 + kb)*64 + lane, planes of 512 KB each.
// R5/R6 verified end-to-end (absmax 0).
// ---------------------------------------------------------------------------

// ---------------------------------------------------------------------------
// prep: protos fp32 (2048x512) -> fp8 e4m3 B image in the layout above.
// (unchanged from R5 — verified)
// ---------------------------------------------------------------------------
__global__ __launch_bounds__(256) void prep_kernel(
    const float* __restrict__ protos, uint8_t* __restrict__ wsB,
    float* __restrict__ y2a, float* __restrict__ rya,
    float* __restrict__ out) {
  const int lane = threadIdx.x & 63;
  const int w    = threadIdx.x >> 6;
  const int c    = blockIdx.x * 4 + w;
  const int g    = c >> 4, cl = c & 15;
  const float4* p = (const float4*)(protos + (size_t)c * 512 + lane * 8);
  float4 f0 = p[0], f1 = p[1];
  float s = f0.x*f0.x + f0.y*f0.y + f0.z*f0.z + f0.w*f0.w
          + f1.x*f1.x + f1.y*f1.y + f1.z*f1.z + f1.w*f1.w;
#pragma unroll
  for (int off = 32; off > 0; off >>= 1) s += __shfl_xor(s, off, 64);
  if (lane == 0) { y2a[c] = s; rya[c] = 1.f / (1.f - s); }
  unsigned ux = cvt4(f0.x, f0.y, f0.z, f0.w);   // k [8l, 8l+4)
  unsigned uy = cvt4(f1.x, f1.y, f1.z, f1.w);   // k [8l+4, 8l+8)
  const int kb = lane >> 4, kg = (lane >> 2) & 3, bo = lane & 3;
  size_t ri  = (size_t)(g * 4 + kb) * 64 + kg * 16 + cl;
  size_t off = ri * 16 + (size_t)(bo & 1) * 8 + (size_t)(bo >> 1) * (512u * 1024u);
  *(uint2*)(wsB + off) = make_uint2(ux, uy);
  if (blockIdx.x == 0 && threadIdx.x == 0) out[0] = 0.f;
}

// ---------------------------------------------------------------------------
// gemm_min v7: 512 blocks x 512 thr (8 waves), launch_bounds(512,1) -> VGPR
// cap 128 (R3/R6-measured; R6 confirmed NO spill at this cap: WRITE 16 B).
// ROUND-6 DIAGNOSIS: one B-frag per s-iter made LDS the binding pipe —
// 8 ds_read_b128 (96 cyc) per 4 MFMA (34 cyc); 8 MB/CU of LDS reads = 39 us
// floor; measured 63 us with MFMA busy 13 us (= MX floor).  Fix: TWO
// B-frags per s-iter (each A read feeds 2 MFMAs -> LDS floor ~20 us) at a
// DEPTH-2 B pipeline (slots kb&1, prefetch i+2 after the MFMA cluster
// consumes slot i; ~150-200 cyc distance + 4 waves/SIMD covers L2 latency).
// Register budget: Bp 2x2x8=32 + acc 32 + x2r 16 + tmin 16 + temps ~ 125
// = the 128-budget R0 proved spill-free.
//   - wave w: cols [w*256,+256), 8 s-iters x 32 cols (frags g0=w*16+2s,
//     g1=g0+1).
//   - per kb-step: 8 ds_read_b128 (A, 4 rf frags) + 8 MFMA(K=128) + 4
//     global b128 (B prefetch i+2).
//   - floors: LDS ~20 us, MFMA 14.7 us, B-L2 512 MB ~ 15 us.
//   - A staging: byte-identical R5 code on waves 0..3; waves 4..7 issue B
//     warm-up then wait at the single barrier.
// ---------------------------------------------------------------------------
__global__ __launch_bounds__(512, 1) void gemm_min_kernel(
    const float* __restrict__ z, const uint8_t* __restrict__ wsB,
    const float* __restrict__ y2a, const float* __restrict__ rya,
    const float* __restrict__ marg, float* __restrict__ out) {
  __shared__ uint4 AsLo[1024];   // (kb*4 + rf)*64 + lane   (16 KB)
  __shared__ uint4 AsHi[1024];   // same index, k-bytes 16..31 (16 KB)
  __shared__ float x2s[64];
  __shared__ float rxs[64];
  __shared__ float minbuf[64][8];

  const int tid  = threadIdx.x;
  const int lane = tid & 63;
  const int w    = tid >> 6;          // wave 0..7
  const int q    = lane >> 4;         // kg / acc row-group
  const int l15  = lane & 15;
  const size_t rowbase = (size_t)blockIdx.x * 64;

  const uint4* BLo = (const uint4*)wsB;
  const uint4* BHi = BLo + 32768;     // +512 KB

  // ---- B warm-up (i=0,1) first: overlaps the staging barrier ----
  // wave w owns cols [w*256,+256): frag pair g0 = w*16 + 2s, g1 = g0+1.
  // linear step i = s*4 + kb; chunk ri0 = (w*64 + 8s + kb)*64 + lane,
  // ri1 = ri0 + 256; slot = i&1 (= kb&1, since s*4 is even).
  A32 Bp0[2], Bp1[2];
#pragma unroll
  for (int i = 0; i < 2; ++i) {
    size_t r0 = (size_t)(w * 64 + i) * 64 + lane;
    Bp0[i].u4[0] = BLo[r0];       Bp0[i].u4[1] = BHi[r0];
    Bp1[i].u4[0] = BLo[r0 + 256]; Bp1[i].u4[1] = BHi[r0 + 256];
  }

  // ---- A staging + fused x2: waves 0..3 own rows w*16 + l15 (R5 code) ----
  // lane (q,l15): k quarter [q*128, +128) of its row, 4 sub-runs of 32.
  if (w < 4) {
    const float* rp0 = z + (rowbase + w * 16 + l15) * 512 + q * 128;
    float s = 0.f;
#pragma unroll
    for (int t = 0; t < 4; ++t) {
      const float4* rp = (const float4*)(rp0 + t * 32);
      float4 v0 = rp[0], v1 = rp[1], v2 = rp[2], v3 = rp[3];
      float4 v4 = rp[4], v5 = rp[5], v6 = rp[6], v7 = rp[7];
      s += v0.x*v0.x + v0.y*v0.y + v0.z*v0.z + v0.w*v0.w
         + v1.x*v1.x + v1.y*v1.y + v1.z*v1.z + v1.w*v1.w
         + v2.x*v2.x + v2.y*v2.y + v2.z*v2.z + v2.w*v2.w
         + v3.x*v3.x + v3.y*v3.y + v3.z*v3.z + v3.w*v3.w
         + v4.x*v4.x + v4.y*v4.y + v4.z*v4.z + v4.w*v4.w
         + v5.x*v5.x + v5.y*v5.y + v5.z*v5.z + v5.w*v5.w
         + v6.x*v6.x + v6.y*v6.y + v6.z*v6.z + v6.w*v6.w
         + v7.x*v7.x + v7.y*v7.y + v7.z*v7.z + v7.w*v7.w;
      uint4 lo, hi;
      lo.x = cvt4(v0.x, v0.y, v0.z, v0.w);
      lo.y = cvt4(v1.x, v1.y, v1.z, v1.w);
      lo.z = cvt4(v2.x, v2.y, v2.z, v2.w);
      lo.w = cvt4(v3.x, v3.y, v3.z, v3.w);
      hi.x = cvt4(v4.x, v4.y, v4.z, v4.w);
      hi.y = cvt4(v5.x, v5.y, v5.z, v5.w);
      hi.z = cvt4(v6.x, v6.y, v6.z, v6.w);
      hi.w = cvt4(v7.x, v7.y, v7.z, v7.w);
      int ri = (q * 4 + w) * 64 + t * 16 + l15;   // chunk (kb=q, rf=w), kg=t
      AsLo[ri] = lo; AsHi[ri] = hi;
    }
    s += __shfl_xor(s, 16, 64);
    s += __shfl_xor(s, 32, 64);      // sum over the 4 q-lanes of this row
    if (lane < 16) { x2s[w * 16 + lane] = s; rxs[w * 16 + lane] = 1.f / (1.f - s); }
  }
  __syncthreads();  // the ONLY barrier before the final reduction

  // x2 resident per lane: rows rf*16 + q*4 + r
  float x2r[4][4];
#pragma unroll
  for (int rf = 0; rf < 4; ++rf) {
    float4 x4 = *(const float4*)&x2s[rf * 16 + q * 4];
    x2r[rf][0] = x4.x; x2r[rf][1] = x4.y; x2r[rf][2] = x4.z; x2r[rf][3] = x4.w;
  }

  float tmin[4][4];
#pragma unroll
  for (int rf = 0; rf < 4; ++rf)
#pragma unroll
    for (int r = 0; r < 4; ++r) tmin[rf][r] = 3.4e38f;

  const float* y2p = y2a + w * 256 + l15;
  const float* ryp = rya + w * 256 + l15;

#pragma clang loop unroll(disable)
  for (int s = 0; s < 8; ++s) {
    f32x4 acc[4][2];
#pragma unroll
    for (int rf = 0; rf < 4; ++rf) {
      f32x4 z4 = {0.f, 0.f, 0.f, 0.f};
      acc[rf][0] = z4; acc[rf][1] = z4;
    }
    float y2v0 = y2p[s * 32],      ryv0 = ryp[s * 32];
    float y2v1 = y2p[s * 32 + 16], ryv1 = ryp[s * 32 + 16];

#pragma unroll
    for (int kb = 0; kb < 4; ++kb) {
      // consume slot kb&1 (loaded 2 steps ago)
#pragma unroll
      for (int rf = 0; rf < 4; ++rf) {
        A32 a;
        int ri = (kb * 4 + rf) * 64 + lane;
        a.u4[0] = AsLo[ri];
        a.u4[1] = AsHi[ri];
        acc[rf][0] = MFMA128(a.v, Bp0[kb & 1].v, acc[rf][0]);
        acc[rf][1] = MFMA128(a.v, Bp1[kb & 1].v, acc[rf][1]);
      }
      {  // prefetch step i+2 into the just-consumed slot (pad absorbs tail)
        int ip = s * 4 + kb + 2;
        size_t r0 = (size_t)(w * 64 + (ip >> 2) * 8 + (ip & 3)) * 64 + lane;
        Bp0[kb & 1].u4[0] = BLo[r0];       Bp0[kb & 1].u4[1] = BHi[r0];
        Bp1[kb & 1].u4[0] = BLo[r0 + 256]; Bp1[kb & 1].u4[1] = BHi[r0 + 256];
      }
    }

    // epilogue: cols c0 = w*256 + s*32 + l15, c1 = c0 + 16
#pragma unroll
    for (int rf = 0; rf < 4; ++rf) {
#pragma unroll
      for (int r = 0; r < 4; ++r) {
        float xv = x2r[rf][r];
        float u0 = fmaxf(fmaf(-2.f, acc[rf][0][r], xv + y2v0), 0.f) * ryv0;
        float u1 = fmaxf(fmaf(-2.f, acc[rf][1][r], xv + y2v1), 0.f) * ryv1;
        tmin[rf][r] = fminf(tmin[rf][r], fminf(u0, u1));
      }
    }
  }

  // ---- min across the 16 lanes (l15) sharing each row ----
#pragma unroll
  for (int rf = 0; rf < 4; ++rf) {
#pragma unroll
    for (int r = 0; r < 4; ++r) {
      float v = tmin[rf][r];
      v = fminf(v, __shfl_xor(v, 1, 64));
      v = fminf(v, __shfl_xor(v, 2, 64));
      v = fminf(v, __shfl_xor(v, 4, 64));
      v = fminf(v, __shfl_xor(v, 8, 64));
      if (l15 == 0) minbuf[rf * 16 + q * 4 + r][w] = v;
    }
  }
  __syncthreads();

  if (w == 0) {  // lane = row 0..63
    float m = minbuf[lane][0];
#pragma unroll
    for (int i = 1; i < 8; ++i) m = fminf(m, minbuf[lane][i]);
    float t = m * rxs[lane];                 // fold 1/(1-x2) once per row
    float arg = fmaxf(fmaf(2.f, t, 1.f), 1.f + EPS_F);
    float contrib = fmaxf(marg[0] - acoshf(arg), 0.f);
#pragma unroll
    for (int off = 32; off > 0; off >>= 1) contrib += __shfl_xor(contrib, off, 64);
    if (lane == 0) atomicAdd(out, contrib * (1.0f / 32768.f));
  }
}

// ---------------------------------------------------------------------------
extern "C" void kernel_launch(void* const* d_in, const int* in_sizes, int n_in,
                              void* d_out, int out_size, void* d_ws, size_t ws_size,
                              hipStream_t stream) {
  const float* z      = (const float*)d_in[0];  // 32768 x 512 fp32
  const float* protos = (const float*)d_in[1];  // 2048 x 512 fp32
  const float* marg   = (const float*)d_in[2];  // scalar
  float* out = (float*)d_out;
  uint8_t* wsB = (uint8_t*)d_ws;                // 1 MB image (lo/hi 512 KB planes)
  // 192 KB pad absorbs the harmless B-pipeline tail over-reads (<= 32 KB).
  float* y2a = (float*)((char*)d_ws + (1 << 20) + 192 * 1024);   // 8 KB
  float* rya = y2a + 2048;                                       // 8 KB

  prep_kernel<<<512, 256, 0, stream>>>(protos, wsB, y2a, rya, out);
  gemm_min_kernel<<<512, 512, 0, stream>>>(z, wsB, y2a, rya, marg, out);
}